// Round 6
// baseline (8967.710 us; speedup 1.0000x reference)
//
#include <hip/hip_runtime.h>
#include <math.h>

// ModalityRouter: logits = x @ gate_w^T (M=32768, K=2048, N=64),
// top-2 -> softmax -> gates/indices/load/top_logits.
//
// Round-6 design: lane = token, acc[64] experts in VGPRs, w via SCALAR loads.
//  - Round-5 post-mortem: 17 GB scratch writes (wv[16] spilled, VGPR=64).
//    Fix: per-thread live set = acc[64] + x[32] + addr ~ 110 regs, static
//    indexing everywhere, no big arrays.
//  - gate_w (512 KB, L2/K$-resident) is wave-uniform -> s_load_dwordx16
//    window; x per-lane float4 stream (each lane consumes full 64B lines).
//  - 1 x-load feeds 256 FMAs; NO LDS, NO barriers in main loop.
//  - K split 8 ways across waves; 3-round LDS tree reduce ([e][lane],
//    conflict-free); wave 0: lane-local top-2 scan (lane=token, no shfl),
//    softmax, outputs, LDS load accum, 64 global atomics.

#define NE       64
#define KD       2048
#define TOKB     64            // tokens per block = lanes per wave
#define NWAVE    8             // waves per block (K-split)
#define KPW      (KD / NWAVE)  // 256 k per wave
#define KB       16            // k per inner block
#define NKB      (KPW / KB)    // 16
#define M_TOTAL  32768
#define IDX_OFF  65536
#define LOAD_OFF 131072
#define TL_OFF   131136
#define NEG_INF  -3.0e38f

__global__ __launch_bounds__(512, 4)
void router_kernel(const float* __restrict__ x,
                   const float* __restrict__ gw,
                   float* __restrict__ out)
{
    __shared__ float red[4][NE][TOKB];   // 64 KB: [partial][expert][lane]
    __shared__ float sload[NE];

    const int tid  = threadIdx.x;
    const int wave = tid >> 6;
    const int lane = tid & 63;                       // token within block
    const long tok = (long)blockIdx.x * TOKB + lane;

    if (tid < NE) sload[tid] = 0.0f;

    const float* xp = x + (size_t)tok * KD + wave * KPW;   // per-lane row
    const float* wp = gw + wave * KPW;                     // uniform base

    float acc[NE];
#pragma unroll
    for (int e = 0; e < NE; ++e) acc[e] = 0.0f;

    float4 xc[KB / 4], xn[KB / 4];
#pragma unroll
    for (int j = 0; j < KB / 4; ++j)
        xc[j] = *reinterpret_cast<const float4*>(xp + 4 * j);

#pragma unroll 1
    for (int kb = 0; kb < NKB; ++kb) {
        const int k0 = kb * KB;

        // prefetch next x block (consumed ~2048 FMA-cycles later)
        if (kb + 1 < NKB) {
#pragma unroll
            for (int j = 0; j < KB / 4; ++j)
                xn[j] = *reinterpret_cast<const float4*>(xp + k0 + KB + 4 * j);
        }

        // 64 experts x 16 k; w addresses wave-uniform -> scalar loads
#pragma unroll
        for (int e = 0; e < NE; ++e) {
            const float* wr = wp + (size_t)e * KD + k0;
#pragma unroll
            for (int q = 0; q < KB / 4; ++q) {
                acc[e] = fmaf(xc[q].x, wr[4 * q + 0], acc[e]);
                acc[e] = fmaf(xc[q].y, wr[4 * q + 1], acc[e]);
                acc[e] = fmaf(xc[q].z, wr[4 * q + 2], acc[e]);
                acc[e] = fmaf(xc[q].w, wr[4 * q + 3], acc[e]);
            }
        }

        if (kb + 1 < NKB) {
#pragma unroll
            for (int j = 0; j < KB / 4; ++j) xc[j] = xn[j];
        }
    }

    // ---- cross-wave K reduction: 8 -> 4 -> 2 -> 1 partials ----
    if (wave >= 4) {
#pragma unroll
        for (int e = 0; e < NE; ++e) red[wave - 4][e][lane] = acc[e];
    }
    __syncthreads();
    if (wave < 4) {
#pragma unroll
        for (int e = 0; e < NE; ++e) acc[e] += red[wave][e][lane];
    }
    __syncthreads();
    if (wave == 2 || wave == 3) {
#pragma unroll
        for (int e = 0; e < NE; ++e) red[wave - 2][e][lane] = acc[e];
    }
    __syncthreads();
    if (wave < 2) {
#pragma unroll
        for (int e = 0; e < NE; ++e) acc[e] += red[wave][e][lane];
    }
    __syncthreads();
    if (wave == 1) {
#pragma unroll
        for (int e = 0; e < NE; ++e) red[0][e][lane] = acc[e];
    }
    __syncthreads();

    if (wave == 0) {
#pragma unroll
        for (int e = 0; e < NE; ++e) acc[e] += red[0][e][lane];

        // lane-local top-2 (ascending scan, strict > => lowest index on ties,
        // matching lax.top_k)
        float v0 = NEG_INF; int i0 = 0;
#pragma unroll
        for (int e = 0; e < NE; ++e) {
            if (acc[e] > v0) { v0 = acc[e]; i0 = e; }
        }
        float v1 = NEG_INF; int i1 = 0;
#pragma unroll
        for (int e = 0; e < NE; ++e) {
            if (e != i0 && acc[e] > v1) { v1 = acc[e]; i1 = e; }
        }

        const float g1 = 1.0f / (1.0f + expf(v0 - v1));  // stable: v0 >= v1
        const float g0 = 1.0f - g1;
        const size_t gt = (size_t)blockIdx.x * TOKB + lane;
        out[gt * 2 + 0] = g0;
        out[gt * 2 + 1] = g1;
        out[IDX_OFF + gt * 2 + 0] = (float)i0;
        out[IDX_OFF + gt * 2 + 1] = (float)i1;
        out[TL_OFF + gt * 2 + 0] = v0;
        out[TL_OFF + gt * 2 + 1] = v1;
        atomicAdd(&sload[i0], g0);
        atomicAdd(&sload[i1], g1);
    }
    __syncthreads();
    if (tid < NE) atomicAdd(out + LOAD_OFF + tid, sload[tid]);
}

extern "C" void kernel_launch(void* const* d_in, const int* in_sizes, int n_in,
                              void* d_out, int out_size, void* d_ws, size_t ws_size,
                              hipStream_t stream)
{
    const float* x  = (const float*)d_in[0];
    const float* gw = (const float*)d_in[1];
    float* out = (float*)d_out;

    hipMemsetAsync(out + LOAD_OFF, 0, NE * sizeof(float), stream);
    router_kernel<<<dim3(M_TOTAL / TOKB), dim3(512), 0, stream>>>(x, gw, out);
}